// Round 1
// baseline (20112.801 us; speedup 1.0000x reference)
//
#include <hip/hip_runtime.h>
#include <cstdint>
#include <cstddef>

// ---------------- RNG mode: 1 = jax_threefry_partitionable (modern JAX default)
#define RNG_PART 1

// ---------------- sizes
// B=256, T=256, ZS=128, ZT=64, H=512, 3H=1536

// ---------------- workspace layout (float offsets)
static constexpr size_t WT0  = 0;                         // [576][1536]  (w_hh0^T rows 0..511, w_ih0[:, :64]^T rows 512..575)
static constexpr size_t WT1  = WT0 + (size_t)576 * 1536;  // [1024][1536] (w_ih1^T rows 0..511, w_hh1^T rows 512..1023)
static constexpr size_t WIS  = WT1 + (size_t)1024 * 1536; // [512][1536]  (w_ih0[:, 64:]^T)
static constexpr size_t WTH  = WIS + (size_t)512 * 1536;  // [512][64]    head weights gathered, pitch 64
static constexpr size_t ACC0 = WTH + (size_t)512 * 64;    // [256][1536]  static part of xp0 + b_ih0
static constexpr size_t SHH  = ACC0 + (size_t)256 * 1536; // [256][512]   static_h
static constexpr size_t HID  = SHH + (size_t)256 * 512;   // [256][512]   fc1 hidden
static constexpr size_t H0B  = HID + (size_t)256 * 512;   // [2][256][512]
static constexpr size_t H1B  = H0B + (size_t)2 * 256 * 512;
static constexpr size_t LOGB = H1B + (size_t)2 * 256 * 512; // [256][256][64] head logits
static constexpr size_t WS_FLOATS = LOGB + (size_t)256 * 256 * 64;
// fc1T/fc2T alias into LOGB (used only before the step loop)
static constexpr size_t FC1T = LOGB;                 // [128][512]
static constexpr size_t FC2T = LOGB + 128 * 512;     // [512][512]

// ---------------- output layout (float offsets)
static constexpr size_t O_SCONT = 0;           // [256][16]
static constexpr size_t O_SCAT  = 4096;        // [256][10]
static constexpr size_t O_TCONT = 6656;        // [256][256][32]
static constexpr size_t O_IRR0  = 2103808;     // [256][256][2]
static constexpr size_t O_IRR1  = 2234880;     // [256][256][2]
static constexpr size_t O_CAT0  = 2365952;     // [256][256][8]
static constexpr size_t O_CAT1  = 2890240;     // [256][256][16]
static constexpr size_t O_VMASK = 3938816;     // [256][256]
static constexpr size_t O_VTIME = 4004352;     // [256][256]

// ---------------- threefry2x32-20 (matches JAX / Random123)
__host__ __device__ inline void tf2x32(unsigned k0, unsigned k1, unsigned x0, unsigned x1,
                                       unsigned* o0, unsigned* o1) {
  unsigned ks2 = k0 ^ k1 ^ 0x1BD11BDAu;
#define TFR(r) { x0 += x1; x1 = (x1 << (r)) | (x1 >> (32 - (r))); x1 ^= x0; }
  x0 += k0; x1 += k1;
  TFR(13) TFR(15) TFR(26) TFR(6)
  x0 += k1; x1 += ks2 + 1u;
  TFR(17) TFR(29) TFR(16) TFR(24)
  x0 += ks2; x1 += k0 + 2u;
  TFR(13) TFR(15) TFR(26) TFR(6)
  x0 += k0; x1 += k1 + 3u;
  TFR(17) TFR(29) TFR(16) TFR(24)
  x0 += k1; x1 += ks2 + 4u;
  TFR(13) TFR(15) TFR(26) TFR(6)
  x0 += ks2; x1 += k0 + 5u;
#undef TFR
  *o0 = x0; *o1 = x1;
}

__device__ inline float rng_uniform_n(unsigned k0, unsigned k1, unsigned idx, unsigned n) {
  unsigned o0, o1, bits;
#if RNG_PART
  (void)n;
  tf2x32(k0, k1, 0u, idx, &o0, &o1);
  bits = o0 ^ o1;
#else
  unsigned half = n >> 1;
  unsigned l = (idx < half) ? idx : idx - half;
  tf2x32(k0, k1, l, half + l, &o0, &o1);
  bits = (idx < half) ? o0 : o1;
#endif
  return __uint_as_float((bits >> 9) | 0x3f800000u) - 1.0f;
}

__device__ inline float sigmoidf_(float x) { return 1.0f / (1.0f + expf(-x)); }

// ---------------- tiled transpose: dst[k*dstStride + j] = src[j*srcStride + k]
__global__ __launch_bounds__(256) void transpose_k(const float* __restrict__ src, float* __restrict__ dst,
                                                   int J, int K, int srcStride, int dstStride) {
  __shared__ float tile[32][33];
  int kb = blockIdx.x * 32, jb = blockIdx.y * 32;
  int tx = threadIdx.x & 31, ty = threadIdx.x >> 5;
  #pragma unroll
  for (int r = 0; r < 4; ++r) {
    int j = jb + ty + r * 8, k = kb + tx;
    if (j < J && k < K) tile[ty + r * 8][tx] = src[(size_t)j * srcStride + k];
  }
  __syncthreads();
  #pragma unroll
  for (int r = 0; r < 4; ++r) {
    int k = kb + ty + r * 8, j = jb + tx;
    if (k < K && j < J) dst[(size_t)k * dstStride + j] = tile[tx][ty + r * 8];
  }
}

// ---------------- gather head weights into wtH[512][64]
__global__ void hgather_k(const float* __restrict__ time_w, const float* __restrict__ visit_w,
                          const float* __restrict__ tcont_w, const float* __restrict__ irr0_w,
                          const float* __restrict__ irr1_w, const float* __restrict__ cat0_w,
                          const float* __restrict__ cat1_w, float* __restrict__ wtH) {
  int c = blockIdx.x;
  const float* src;
  if (c == 0) src = time_w;
  else if (c == 1) src = visit_w;
  else if (c < 34) src = tcont_w + (size_t)(c - 2) * 512;
  else if (c == 34) src = irr0_w;
  else if (c == 35) src = irr1_w;
  else if (c < 44) src = cat0_w + (size_t)(c - 36) * 512;
  else src = cat1_w + (size_t)(c - 44) * 512;
  for (int k = threadIdx.x; k < 512; k += blockDim.x) wtH[(size_t)k * 64 + c] = src[k];
}

// ---------------- generic GEMM: out[m][j] = sum_k in[m][k]*wT[k][j] + bias[j], optional relu
__global__ __launch_bounds__(128) void gemm_k(const float* __restrict__ in, const float* __restrict__ wT,
                                              const float* __restrict__ bias, float* __restrict__ out,
                                              int M, int K, int J, int relu) {
  __shared__ float ibuf[64][34];
  __shared__ float wbuf[64][36];
  int jt = blockIdx.x % (J >> 5), mt = blockIdx.x / (J >> 5);
  int m0 = mt * 32, j0 = jt * 32;
  int tid = threadIdx.x;
  int mq = tid & 15, jq = tid >> 4;
  float acc[2][4] = {{0.f, 0.f, 0.f, 0.f}, {0.f, 0.f, 0.f, 0.f}};
  for (int kc = 0; kc < K; kc += 64) {
    __syncthreads();
    #pragma unroll
    for (int i = 0; i < 16; ++i) {
      int lin = i * 128 + tid;
      int k = lin & 63, m = lin >> 6;
      ibuf[k][m] = in[(size_t)(m0 + m) * K + kc + k];
    }
    #pragma unroll
    for (int i = 0; i < 16; ++i) {
      int lin = i * 128 + tid;
      int c = lin & 31, k = lin >> 5;
      wbuf[k][c] = wT[(size_t)(kc + k) * J + j0 + c];
    }
    __syncthreads();
    #pragma unroll 8
    for (int k = 0; k < 64; ++k) {
      float i0 = ibuf[k][2 * mq], i1 = ibuf[k][2 * mq + 1];
      const float4 w = *(const float4*)&wbuf[k][4 * jq];
      acc[0][0] += i0 * w.x; acc[0][1] += i0 * w.y; acc[0][2] += i0 * w.z; acc[0][3] += i0 * w.w;
      acc[1][0] += i1 * w.x; acc[1][1] += i1 * w.y; acc[1][2] += i1 * w.z; acc[1][3] += i1 * w.w;
    }
  }
  #pragma unroll
  for (int mi = 0; mi < 2; ++mi)
    #pragma unroll
    for (int ji = 0; ji < 4; ++ji) {
      int j = j0 + 4 * jq + ji;
      float v = acc[mi][ji] + bias[j];
      if (relu) v = fmaxf(v, 0.0f);
      out[(size_t)(m0 + 2 * mq + mi) * J + j] = v;
    }
}

// ---------------- fused per-step kernel: A = h0 update, B = h1 update (t-1), C = head logits (t-2)
struct HeadPtrs {
  const float *time_b, *visit_b, *tcont_b, *irr0_b, *irr1_b, *cat0_b, *cat1_b;
};

__device__ inline float head_bias(const HeadPtrs& hp, int c) {
  if (c == 0) return hp.time_b[0];
  if (c == 1) return hp.visit_b[0];
  if (c < 34) return hp.tcont_b[c - 2];
  if (c == 34) return hp.irr0_b[0];
  if (c == 35) return hp.irr1_b[0];
  if (c < 44) return hp.cat0_b[c - 36];
  return hp.cat1_b[c - 44];
}

#define GATE_FMA(TGT) \
  { float hv0 = hbuf[k][2 * bq], hv1 = hbuf[k][2 * bq + 1]; \
    float wr0 = wbuf[k][2 * hq], wr1 = wbuf[k][2 * hq + 1]; \
    float wz0 = wbuf[k][16 + 2 * hq], wz1 = wbuf[k][16 + 2 * hq + 1]; \
    float wn0 = wbuf[k][32 + 2 * hq], wn1 = wbuf[k][32 + 2 * hq + 1]; \
    ar[0][0] += hv0 * wr0; ar[0][1] += hv0 * wr1; ar[1][0] += hv1 * wr0; ar[1][1] += hv1 * wr1; \
    az[0][0] += hv0 * wz0; az[0][1] += hv0 * wz1; az[1][0] += hv1 * wz0; az[1][1] += hv1 * wz1; \
    TGT[0][0] += hv0 * wn0; TGT[0][1] += hv0 * wn1; TGT[1][0] += hv1 * wn0; TGT[1][1] += hv1 * wn1; }

__global__ __launch_bounds__(128) void step_k(int s,
    const float* __restrict__ z_temporal,
    const float* __restrict__ b_hh0,
    const float* __restrict__ b_ih1, const float* __restrict__ b_hh1,
    float* __restrict__ ws, HeadPtrs hp)
{
  __shared__ float hbuf[128][34];
  __shared__ float wbuf[128][64];
  int blk = blockIdx.x, tid = threadIdx.x;

  if (blk < 256) {
    // ---- job A: h0_s = GRUcell0(z_s, h0_{s-1}); s in [0,255]
    if (s > 255) return;
    int btile = blk >> 5, htile = blk & 31;
    int b0 = btile * 32, hc0 = htile * 16;
    int bq = tid & 15, hq = tid >> 4;
    const float* hprev = ws + H0B + (size_t)((s + 1) & 1) * 131072;
    float*       hcur  = ws + H0B + (size_t)(s & 1) * 131072;
    const float* wt0 = ws + WT0;
    const float* acc0 = ws + ACC0;
    float ar[2][2], az[2][2], ain[2][2], ahn[2][2];
    #pragma unroll
    for (int bi = 0; bi < 2; ++bi)
      #pragma unroll
      for (int hj = 0; hj < 2; ++hj) {
        int b = b0 + 2 * bq + bi, h = hc0 + 2 * hq + hj;
        ar[bi][hj]  = acc0[(size_t)b * 1536 + h] + b_hh0[h];
        az[bi][hj]  = acc0[(size_t)b * 1536 + 512 + h] + b_hh0[512 + h];
        ain[bi][hj] = acc0[(size_t)b * 1536 + 1024 + h];
        ahn[bi][hj] = b_hh0[1024 + h];
      }
    for (int kc = 0; kc < 4; ++kc) {
      __syncthreads();
      #pragma unroll
      for (int i = 0; i < 32; ++i) {
        int lin = i * 128 + tid;
        int k = lin & 127, bb = lin >> 7;
        hbuf[k][bb] = hprev[(size_t)(b0 + bb) * 512 + kc * 128 + k];
      }
      #pragma unroll
      for (int i = 0; i < 48; ++i) {
        int lin = i * 128 + tid;
        int c = lin % 48, k = lin / 48;
        int j = (c >> 4) * 512 + hc0 + (c & 15);
        wbuf[k][c] = wt0[(size_t)(kc * 128 + k) * 1536 + j];
      }
      __syncthreads();
      #pragma unroll 8
      for (int k = 0; k < 128; ++k) GATE_FMA(ahn)
    }
    // z chunk (K = 64), input side -> ain
    __syncthreads();
    #pragma unroll
    for (int i = 0; i < 16; ++i) {
      int lin = i * 128 + tid;
      int k = lin & 63, bb = lin >> 6;
      hbuf[k][bb] = z_temporal[(size_t)(b0 + bb) * 16384 + (size_t)s * 64 + k];
    }
    #pragma unroll
    for (int i = 0; i < 24; ++i) {
      int lin = i * 128 + tid;
      int c = lin % 48, k = lin / 48;
      int j = (c >> 4) * 512 + hc0 + (c & 15);
      wbuf[k][c] = wt0[(size_t)(512 + k) * 1536 + j];
    }
    __syncthreads();
    #pragma unroll 8
    for (int k = 0; k < 64; ++k) GATE_FMA(ain)
    #pragma unroll
    for (int bi = 0; bi < 2; ++bi)
      #pragma unroll
      for (int hj = 0; hj < 2; ++hj) {
        int b = b0 + 2 * bq + bi, h = hc0 + 2 * hq + hj;
        float r = sigmoidf_(ar[bi][hj]);
        float zg = sigmoidf_(az[bi][hj]);
        float n = tanhf(ain[bi][hj] + r * ahn[bi][hj]);
        float hold = hprev[(size_t)b * 512 + h];
        hcur[(size_t)b * 512 + h] = (1.0f - zg) * n + zg * hold;
      }
  } else if (blk < 512) {
    // ---- job B: h1_{s-1} = GRUcell1(h0_{s-1} @ w_ih1^T, h1_{s-2}); s in [1,256]
    if (s < 1 || s > 256) return;
    int cb = blk - 256;
    int btile = cb >> 5, htile = cb & 31;
    int b0 = btile * 32, hc0 = htile * 16;
    int bq = tid & 15, hq = tid >> 4;
    const float* h0src = ws + H0B + (size_t)((s - 1) & 1) * 131072;
    const float* h1old = ws + H1B + (size_t)(s & 1) * 131072;
    float*       h1cur = ws + H1B + (size_t)((s - 1) & 1) * 131072;
    const float* wt1 = ws + WT1;
    float ar[2][2], az[2][2], ain[2][2], ahn[2][2];
    #pragma unroll
    for (int bi = 0; bi < 2; ++bi)
      #pragma unroll
      for (int hj = 0; hj < 2; ++hj) {
        int h = hc0 + 2 * hq + hj;
        ar[bi][hj]  = b_ih1[h] + b_hh1[h];
        az[bi][hj]  = b_ih1[512 + h] + b_hh1[512 + h];
        ain[bi][hj] = b_ih1[1024 + h];
        ahn[bi][hj] = b_hh1[1024 + h];
      }
    for (int kc = 0; kc < 8; ++kc) {
      const float* src = (kc < 4) ? h0src : h1old;
      int kofs = (kc & 3) << 7;
      __syncthreads();
      #pragma unroll
      for (int i = 0; i < 32; ++i) {
        int lin = i * 128 + tid;
        int k = lin & 127, bb = lin >> 7;
        hbuf[k][bb] = src[(size_t)(b0 + bb) * 512 + kofs + k];
      }
      #pragma unroll
      for (int i = 0; i < 48; ++i) {
        int lin = i * 128 + tid;
        int c = lin % 48, k = lin / 48;
        int j = (c >> 4) * 512 + hc0 + (c & 15);
        wbuf[k][c] = wt1[(size_t)(kc * 128 + k) * 1536 + j];
      }
      __syncthreads();
      if (kc < 4) {
        #pragma unroll 8
        for (int k = 0; k < 128; ++k) GATE_FMA(ain)
      } else {
        #pragma unroll 8
        for (int k = 0; k < 128; ++k) GATE_FMA(ahn)
      }
    }
    #pragma unroll
    for (int bi = 0; bi < 2; ++bi)
      #pragma unroll
      for (int hj = 0; hj < 2; ++hj) {
        int b = b0 + 2 * bq + bi, h = hc0 + 2 * hq + hj;
        float r = sigmoidf_(ar[bi][hj]);
        float zg = sigmoidf_(az[bi][hj]);
        float n = tanhf(ain[bi][hj] + r * ahn[bi][hj]);
        float hold = h1old[(size_t)b * 512 + h];
        h1cur[(size_t)b * 512 + h] = (1.0f - zg) * n + zg * hold;
      }
  } else {
    // ---- job C: head logits for t = s-2 from h1_{s-2}; s in [2,257]
    if (s < 2) return;
    int cb = blk - 512;
    int b0 = cb * 32;
    int bq = tid & 15, cq = tid >> 4;
    const float* h1 = ws + H1B + (size_t)(s & 1) * 131072;
    const float* wtH = ws + WTH;
    float acc[2][8] = {};
    for (int kc = 0; kc < 4; ++kc) {
      __syncthreads();
      #pragma unroll
      for (int i = 0; i < 32; ++i) {
        int lin = i * 128 + tid;
        int k = lin & 127, bb = lin >> 7;
        hbuf[k][bb] = h1[(size_t)(b0 + bb) * 512 + kc * 128 + k];
      }
      #pragma unroll
      for (int i = 0; i < 64; ++i) {
        int lin = i * 128 + tid;
        int c = lin & 63, k = lin >> 6;
        wbuf[k][c] = wtH[(size_t)(kc * 128 + k) * 64 + c];
      }
      __syncthreads();
      #pragma unroll 4
      for (int k = 0; k < 128; ++k) {
        float hv0 = hbuf[k][2 * bq], hv1 = hbuf[k][2 * bq + 1];
        const float4 wA = *(const float4*)&wbuf[k][cq * 8];
        const float4 wB = *(const float4*)&wbuf[k][cq * 8 + 4];
        acc[0][0] += hv0 * wA.x; acc[0][1] += hv0 * wA.y; acc[0][2] += hv0 * wA.z; acc[0][3] += hv0 * wA.w;
        acc[0][4] += hv0 * wB.x; acc[0][5] += hv0 * wB.y; acc[0][6] += hv0 * wB.z; acc[0][7] += hv0 * wB.w;
        acc[1][0] += hv1 * wA.x; acc[1][1] += hv1 * wA.y; acc[1][2] += hv1 * wA.z; acc[1][3] += hv1 * wA.w;
        acc[1][4] += hv1 * wB.x; acc[1][5] += hv1 * wB.y; acc[1][6] += hv1 * wB.z; acc[1][7] += hv1 * wB.w;
      }
    }
    int t = s - 2;
    float* lg = ws + LOGB;
    #pragma unroll
    for (int bi = 0; bi < 2; ++bi)
      #pragma unroll
      for (int ci = 0; ci < 8; ++ci) {
        int c = cq * 8 + ci;
        if (c < 60) {
          int b = b0 + 2 * bq + bi;
          lg[((size_t)b * 256 + t) * 64 + c] = acc[bi][ci] + head_bias(hp, c);
        }
      }
  }
}

// ---------------- static heads
__global__ __launch_bounds__(64) void static_heads_k(const float* __restrict__ sh_buf,
    const float* __restrict__ scont_w, const float* __restrict__ scont_b,
    const float* __restrict__ scat_w, const float* __restrict__ scat_b,
    float* __restrict__ out, unsigned ks0, unsigned ks1)
{
  __shared__ float hrow[512];
  __shared__ float xl[10];
  __shared__ float yv[10];
  __shared__ int argsh;
  int b = blockIdx.x, tid = threadIdx.x;
  const float* hr = sh_buf + (size_t)b * 512;
  for (int i = tid; i < 512; i += 64) hrow[i] = hr[i];
  __syncthreads();
  if (tid < 16) {
    float a = 0.f;
    const float* w = scont_w + (size_t)tid * 512;
    for (int k = 0; k < 512; ++k) a += hrow[k] * w[k];
    out[O_SCONT + (size_t)b * 16 + tid] = a + scont_b[tid];
  }
  if (tid < 10) {
    float a = 0.f;
    const float* w = scat_w + (size_t)tid * 512;
    for (int k = 0; k < 512; ++k) a += hrow[k] * w[k];
    a += scat_b[tid];
    float u = rng_uniform_n(ks0, ks1, (unsigned)(b * 10 + tid), 2560u);
    u = fmaxf(1e-9f, u + 1e-9f);
    float g = -logf(-logf(u));
    xl[tid] = a + g;
  }
  __syncthreads();
  if (tid == 0) {
    float m = xl[0];
    for (int c = 1; c < 10; ++c) m = fmaxf(m, xl[c]);
    float ssum = 0.f;
    for (int c = 0; c < 10; ++c) { yv[c] = expf(xl[c] - m); ssum += yv[c]; }
    int arg = 0; float best = -1.0f;
    for (int c = 0; c < 10; ++c) { yv[c] = yv[c] / ssum; if (yv[c] > best) { best = yv[c]; arg = c; } }
    argsh = arg;
  }
  __syncthreads();
  if (tid < 10) {
    float y = yv[tid];
    out[O_SCAT + (size_t)b * 10 + tid] = (tid == argsh) ? ((1.0f + y) - y) : 0.0f;
  }
}

// ---------------- final scans + sampling + emission
struct Keys { unsigned kv0, kv1, ki00, ki01, ki10, ki11, kc00, kc01, kc10, kc11; };

__global__ __launch_bounds__(256) void final_k(const float* __restrict__ ws, float* __restrict__ out, Keys ky)
{
  __shared__ float sh[256];
  __shared__ unsigned shu[256];
  int b = blockIdx.x, t = threadIdx.x;
  int idx = b * 256 + t;
  const float* lg = ws + LOGB + (size_t)idx * 64;
  float l0 = lg[0], l1 = lg[1], l34 = lg[34], l35 = lg[35];

  // delta_t = softplus(time logit); inclusive cumsum; normalize by max (= last, monotone)
  float dt = fmaxf(l0, 0.0f) + log1pf(expf(-fabsf(l0)));
  sh[t] = dt; __syncthreads();
  for (int off = 1; off < 256; off <<= 1) {
    float v = (t >= off) ? sh[t - off] : 0.0f;
    __syncthreads();
    sh[t] += v;
    __syncthreads();
  }
  float vt = sh[t];
  float denom = sh[255] + 1e-8f;
  out[O_VTIME + idx] = vt / denom;
  __syncthreads();

  // visit mask: vm[0]=1, else u<p ; cumprod => prefix AND
  float pv = sigmoidf_(l1);
  float uv = rng_uniform_n(ky.kv0, ky.kv1, (unsigned)idx, 65536u);
  shu[t] = (t == 0) ? 1u : (uv < pv ? 1u : 0u);
  __syncthreads();
  for (int off = 1; off < 256; off <<= 1) {
    unsigned v = (t >= off) ? shu[t - off] : 1u;
    __syncthreads();
    shu[t] &= v;
    __syncthreads();
  }
  float mask = (float)shu[t];
  out[O_VMASK + idx] = mask;
  __syncthreads();

  // irr0: flip iff (u < hazard) before first flip -> prefix OR of (u<h)
  {
    float hz = sigmoidf_(l34);
    float u = rng_uniform_n(ky.ki00, ky.ki01, (unsigned)idx, 65536u);
    shu[t] = (u < hz) ? 1u : 0u;
    __syncthreads();
    for (int off = 1; off < 256; off <<= 1) {
      unsigned v = (t >= off) ? shu[t - off] : 0u;
      __syncthreads();
      shu[t] |= v;
      __syncthreads();
    }
    float st = (float)shu[t];
    out[O_IRR0 + (size_t)idx * 2]     = (1.0f - st) * mask;
    out[O_IRR0 + (size_t)idx * 2 + 1] = st * mask;
    __syncthreads();
  }
  // irr1
  {
    float hz = sigmoidf_(l35);
    float u = rng_uniform_n(ky.ki10, ky.ki11, (unsigned)idx, 65536u);
    shu[t] = (u < hz) ? 1u : 0u;
    __syncthreads();
    for (int off = 1; off < 256; off <<= 1) {
      unsigned v = (t >= off) ? shu[t - off] : 0u;
      __syncthreads();
      shu[t] |= v;
      __syncthreads();
    }
    float st = (float)shu[t];
    out[O_IRR1 + (size_t)idx * 2]     = (1.0f - st) * mask;
    out[O_IRR1 + (size_t)idx * 2 + 1] = st * mask;
  }

  // temporal_cont
  #pragma unroll
  for (int c = 0; c < 32; ++c)
    out[O_TCONT + (size_t)idx * 32 + c] = lg[2 + c] * mask;

  // cat0 (8-way gumbel straight-through)
  {
    float x[8], y[8];
    float m = -1e30f;
    #pragma unroll
    for (int c = 0; c < 8; ++c) {
      float u = rng_uniform_n(ky.kc00, ky.kc01, (unsigned)idx * 8u + c, 524288u);
      u = fmaxf(1e-9f, u + 1e-9f);
      float g = -logf(-logf(u));
      x[c] = lg[36 + c] + g;
      m = fmaxf(m, x[c]);
    }
    float ssum = 0.f;
    #pragma unroll
    for (int c = 0; c < 8; ++c) { y[c] = expf(x[c] - m); ssum += y[c]; }
    int arg = 0; float best = -1.0f;
    #pragma unroll
    for (int c = 0; c < 8; ++c) { y[c] /= ssum; if (y[c] > best) { best = y[c]; arg = c; } }
    #pragma unroll
    for (int c = 0; c < 8; ++c)
      out[O_CAT0 + (size_t)idx * 8 + c] = (c == arg) ? ((1.0f + y[c]) - y[c]) * mask : 0.0f;
  }
  // cat1 (16-way)
  {
    float x[16], y[16];
    float m = -1e30f;
    #pragma unroll
    for (int c = 0; c < 16; ++c) {
      float u = rng_uniform_n(ky.kc10, ky.kc11, (unsigned)idx * 16u + c, 1048576u);
      u = fmaxf(1e-9f, u + 1e-9f);
      float g = -logf(-logf(u));
      x[c] = lg[44 + c] + g;
      m = fmaxf(m, x[c]);
    }
    float ssum = 0.f;
    #pragma unroll
    for (int c = 0; c < 16; ++c) { y[c] = expf(x[c] - m); ssum += y[c]; }
    int arg = 0; float best = -1.0f;
    #pragma unroll
    for (int c = 0; c < 16; ++c) { y[c] /= ssum; if (y[c] > best) { best = y[c]; arg = c; } }
    #pragma unroll
    for (int c = 0; c < 16; ++c)
      out[O_CAT1 + (size_t)idx * 16 + c] = (c == arg) ? ((1.0f + y[c]) - y[c]) * mask : 0.0f;
  }
}

// ---------------- host entry
extern "C" void kernel_launch(void* const* d_in, const int* in_sizes, int n_in,
                              void* d_out, int out_size, void* d_ws, size_t ws_size,
                              hipStream_t stream)
{
  (void)in_sizes; (void)n_in; (void)out_size; (void)ws_size;
  const float* z_static   = (const float*)d_in[0];
  const float* z_temporal = (const float*)d_in[1];
  const float* fc1_w = (const float*)d_in[2];
  const float* fc1_b = (const float*)d_in[3];
  const float* fc2_w = (const float*)d_in[4];
  const float* fc2_b = (const float*)d_in[5];
  const float* w_ih0 = (const float*)d_in[6];
  const float* w_hh0 = (const float*)d_in[7];
  const float* b_ih0 = (const float*)d_in[8];
  const float* b_hh0 = (const float*)d_in[9];
  const float* w_ih1 = (const float*)d_in[10];
  const float* w_hh1 = (const float*)d_in[11];
  const float* b_ih1 = (const float*)d_in[12];
  const float* b_hh1 = (const float*)d_in[13];
  const float* time_w = (const float*)d_in[14];
  const float* time_b = (const float*)d_in[15];
  const float* visit_w = (const float*)d_in[16];
  const float* visit_b = (const float*)d_in[17];
  const float* tcont_w = (const float*)d_in[18];
  const float* tcont_b = (const float*)d_in[19];
  const float* irr0_w = (const float*)d_in[20];
  const float* irr0_b = (const float*)d_in[21];
  const float* irr1_w = (const float*)d_in[22];
  const float* irr1_b = (const float*)d_in[23];
  const float* cat0_w = (const float*)d_in[24];
  const float* cat0_b = (const float*)d_in[25];
  const float* cat1_w = (const float*)d_in[26];
  const float* cat1_b = (const float*)d_in[27];
  const float* scont_w = (const float*)d_in[28];
  const float* scont_b = (const float*)d_in[29];
  const float* scat_w = (const float*)d_in[30];
  const float* scat_b = (const float*)d_in[31];
  float* ws = (float*)d_ws;
  float* out = (float*)d_out;

  // weight transposes (aliased fc1T/fc2T live in LOGB region, consumed before step loop)
  transpose_k<<<dim3(16, 48), 256, 0, stream>>>(w_hh0, ws + WT0, 1536, 512, 512, 1536);
  transpose_k<<<dim3(2, 48), 256, 0, stream>>>(w_ih0, ws + WT0 + (size_t)512 * 1536, 1536, 64, 576, 1536);
  transpose_k<<<dim3(16, 48), 256, 0, stream>>>(w_ih1, ws + WT1, 1536, 512, 512, 1536);
  transpose_k<<<dim3(16, 48), 256, 0, stream>>>(w_hh1, ws + WT1 + (size_t)512 * 1536, 1536, 512, 512, 1536);
  transpose_k<<<dim3(16, 48), 256, 0, stream>>>(w_ih0 + 64, ws + WIS, 1536, 512, 576, 1536);
  transpose_k<<<dim3(4, 16), 256, 0, stream>>>(fc1_w, ws + FC1T, 512, 128, 128, 512);
  transpose_k<<<dim3(16, 16), 256, 0, stream>>>(fc2_w, ws + FC2T, 512, 512, 512, 512);
  hgather_k<<<60, 128, 0, stream>>>(time_w, visit_w, tcont_w, irr0_w, irr1_w, cat0_w, cat1_w, ws + WTH);

  // static path: static_h = relu(z_static@fc1^T+b)@fc2^T+b ; acc0 = static_h@w_ih0[:,64:]^T + b_ih0
  gemm_k<<<8 * 16, 128, 0, stream>>>(z_static, ws + FC1T, fc1_b, ws + HID, 256, 128, 512, 1);
  gemm_k<<<8 * 16, 128, 0, stream>>>(ws + HID, ws + FC2T, fc2_b, ws + SHH, 256, 512, 512, 0);
  gemm_k<<<8 * 48, 128, 0, stream>>>(ws + SHH, ws + WIS, b_ih0, ws + ACC0, 256, 512, 1536, 0);

  // RNG keys: key(42) = (0,42); split into 6 children
  unsigned kk[6][2];
#if RNG_PART
  for (int i = 0; i < 6; ++i) tf2x32(0u, 42u, 0u, (unsigned)i, &kk[i][0], &kk[i][1]);
#else
  {
    unsigned flat[12];
    for (int i = 0; i < 6; ++i) {
      unsigned a, bq;
      tf2x32(0u, 42u, (unsigned)i, (unsigned)(6 + i), &a, &bq);
      flat[i] = a; flat[6 + i] = bq;
    }
    for (int i = 0; i < 6; ++i) { kk[i][0] = flat[2 * i]; kk[i][1] = flat[2 * i + 1]; }
  }
#endif
  // order: k_visit, k_i0, k_i1, k_c0, k_c1, k_sc
  static_heads_k<<<256, 64, 0, stream>>>(ws + SHH, scont_w, scont_b, scat_w, scat_b, out, kk[5][0], kk[5][1]);

  // zero initial hidden states (ping-pong buffer index 1)
  hipMemsetAsync((void*)(ws + H0B + 131072), 0, 131072 * sizeof(float), stream);
  hipMemsetAsync((void*)(ws + H1B + 131072), 0, 131072 * sizeof(float), stream);

  HeadPtrs hp{time_b, visit_b, tcont_b, irr0_b, irr1_b, cat0_b, cat1_b};
  for (int s = 0; s <= 257; ++s)
    step_k<<<520, 128, 0, stream>>>(s, z_temporal, b_hh0, b_ih1, b_hh1, ws, hp);

  Keys ky{kk[0][0], kk[0][1], kk[1][0], kk[1][1], kk[2][0], kk[2][1],
          kk[3][0], kk[3][1], kk[4][0], kk[4][1]};
  final_k<<<256, 256, 0, stream>>>(ws, out, ky);
}

// Round 2
// 10306.319 us; speedup vs baseline: 1.9515x; 1.9515x over previous
//
#include <hip/hip_runtime.h>
#include <hip/hip_bf16.h>
#include <cstdint>
#include <cstddef>

#define RNG_PART 1

typedef __bf16 bf16x8 __attribute__((ext_vector_type(8)));
typedef float f32x4 __attribute__((ext_vector_type(4)));
typedef unsigned short ushort_t;

// ---------------- sizes: B=256, T=256, ZS=128, ZT=64, H=512, 3H=1536

// ---------------- workspace layout (float offsets)
static constexpr size_t ACC0 = 0;                  // [256][1536] f32 static part of xp0 (+b_ih0)
static constexpr size_t SHH  = 393216;             // [256][512] static_h
static constexpr size_t HID  = 524288;             // [256][512] fc1 hidden
static constexpr size_t H0F  = 655360;             // [2][256][512] f32 ping-pong h0
static constexpr size_t H1F  = 917504;             // [2][256][512] f32 ping-pong h1
static constexpr size_t LOGB = 1179648;            // [256][256][64] f32 head logits
static constexpr size_t WTH  = 5373952;            // [512][64] f32 gathered head weights
// bf16 regions (float offsets; 2 bf16 per float)
static constexpr size_t H0S  = 5406720;            // [2][3][256][512] bf16 splits of h0
static constexpr size_t H1S  = 5799936;            // [2][3][256][512] bf16 splits of h1
static constexpr size_t WB1  = 6193152;            // [32][32][3][3][64][8] bf16 arranged L1 weights
static constexpr size_t WA0  = 8552448;            // [18][32][3][3][64][8] bf16 arranged L0 weights
static constexpr size_t WH   = 9879552;            // [16][4][3][64][8] bf16 arranged head weights
// aliases into LOGB (consumed before step loop writes LOGB)
static constexpr size_t FC1T = LOGB;               // [128][512]
static constexpr size_t FC2T = LOGB + 65536;       // [512][512]
static constexpr size_t WIS  = FC2T + 262144;      // [512][1536] w_ih0[:,64:]^T

// ---------------- output layout (float offsets)
static constexpr size_t O_SCONT = 0;
static constexpr size_t O_SCAT  = 4096;
static constexpr size_t O_TCONT = 6656;
static constexpr size_t O_IRR0  = 2103808;
static constexpr size_t O_IRR1  = 2234880;
static constexpr size_t O_CAT0  = 2365952;
static constexpr size_t O_CAT1  = 2890240;
static constexpr size_t O_VMASK = 3938816;
static constexpr size_t O_VTIME = 4004352;

// ---------------- threefry2x32-20
__host__ __device__ inline void tf2x32(unsigned k0, unsigned k1, unsigned x0, unsigned x1,
                                       unsigned* o0, unsigned* o1) {
  unsigned ks2 = k0 ^ k1 ^ 0x1BD11BDAu;
#define TFR(r) { x0 += x1; x1 = (x1 << (r)) | (x1 >> (32 - (r))); x1 ^= x0; }
  x0 += k0; x1 += k1;
  TFR(13) TFR(15) TFR(26) TFR(6)
  x0 += k1; x1 += ks2 + 1u;
  TFR(17) TFR(29) TFR(16) TFR(24)
  x0 += ks2; x1 += k0 + 2u;
  TFR(13) TFR(15) TFR(26) TFR(6)
  x0 += k0; x1 += k1 + 3u;
  TFR(17) TFR(29) TFR(16) TFR(24)
  x0 += k1; x1 += ks2 + 4u;
  TFR(13) TFR(15) TFR(26) TFR(6)
  x0 += ks2; x1 += k0 + 5u;
#undef TFR
  *o0 = x0; *o1 = x1;
}

__device__ inline float rng_uniform_n(unsigned k0, unsigned k1, unsigned idx, unsigned n) {
  unsigned o0, o1, bits;
#if RNG_PART
  (void)n;
  tf2x32(k0, k1, 0u, idx, &o0, &o1);
  bits = o0 ^ o1;
#else
  unsigned half = n >> 1;
  unsigned l = (idx < half) ? idx : idx - half;
  tf2x32(k0, k1, l, half + l, &o0, &o1);
  bits = (idx < half) ? o0 : o1;
#endif
  return __uint_as_float((bits >> 9) | 0x3f800000u) - 1.0f;
}

__device__ inline float sigmoidf_(float x) { return 1.0f / (1.0f + expf(-x)); }

// ---------------- tiled transpose: dst[k*dstStride + j] = src[j*srcStride + k]
__global__ __launch_bounds__(256) void transpose_k(const float* __restrict__ src, float* __restrict__ dst,
                                                   int J, int K, int srcStride, int dstStride) {
  __shared__ float tile[32][33];
  int kb = blockIdx.x * 32, jb = blockIdx.y * 32;
  int tx = threadIdx.x & 31, ty = threadIdx.x >> 5;
  #pragma unroll
  for (int r = 0; r < 4; ++r) {
    int j = jb + ty + r * 8, k = kb + tx;
    if (j < J && k < K) tile[ty + r * 8][tx] = src[(size_t)j * srcStride + k];
  }
  __syncthreads();
  #pragma unroll
  for (int r = 0; r < 4; ++r) {
    int k = kb + ty + r * 8, j = jb + tx;
    if (k < K && j < J) dst[(size_t)k * dstStride + j] = tile[tx][ty + r * 8];
  }
}

// ---------------- gather head weights into wtH[512][64] (cols 60..63 zero)
__global__ void hgather_k(const float* __restrict__ time_w, const float* __restrict__ visit_w,
                          const float* __restrict__ tcont_w, const float* __restrict__ irr0_w,
                          const float* __restrict__ irr1_w, const float* __restrict__ cat0_w,
                          const float* __restrict__ cat1_w, float* __restrict__ wtH) {
  int c = blockIdx.x;
  if (c >= 60) {
    for (int k = threadIdx.x; k < 512; k += blockDim.x) wtH[(size_t)k * 64 + c] = 0.0f;
    return;
  }
  const float* src;
  if (c == 0) src = time_w;
  else if (c == 1) src = visit_w;
  else if (c < 34) src = tcont_w + (size_t)(c - 2) * 512;
  else if (c == 34) src = irr0_w;
  else if (c == 35) src = irr1_w;
  else if (c < 44) src = cat0_w + (size_t)(c - 36) * 512;
  else src = cat1_w + (size_t)(c - 44) * 512;
  for (int k = threadIdx.x; k < 512; k += blockDim.x) wtH[(size_t)k * 64 + c] = src[k];
}

// ---------------- generic fp32 GEMM (pre-loop static path only)
__global__ __launch_bounds__(128) void gemm_k(const float* __restrict__ in, const float* __restrict__ wT,
                                              const float* __restrict__ bias, float* __restrict__ out,
                                              int M, int K, int J, int relu) {
  __shared__ float ibuf[64][34];
  __shared__ float wbuf[64][36];
  int jt = blockIdx.x % (J >> 5), mt = blockIdx.x / (J >> 5);
  int m0 = mt * 32, j0 = jt * 32;
  int tid = threadIdx.x;
  int mq = tid & 15, jq = tid >> 4;
  float acc[2][4] = {{0.f, 0.f, 0.f, 0.f}, {0.f, 0.f, 0.f, 0.f}};
  for (int kc = 0; kc < K; kc += 64) {
    __syncthreads();
    #pragma unroll
    for (int i = 0; i < 16; ++i) {
      int lin = i * 128 + tid;
      int k = lin & 63, m = lin >> 6;
      ibuf[k][m] = in[(size_t)(m0 + m) * K + kc + k];
    }
    #pragma unroll
    for (int i = 0; i < 16; ++i) {
      int lin = i * 128 + tid;
      int c = lin & 31, k = lin >> 5;
      wbuf[k][c] = wT[(size_t)(kc + k) * J + j0 + c];
    }
    __syncthreads();
    #pragma unroll 8
    for (int k = 0; k < 64; ++k) {
      float i0 = ibuf[k][2 * mq], i1 = ibuf[k][2 * mq + 1];
      const float4 w = *(const float4*)&wbuf[k][4 * jq];
      acc[0][0] += i0 * w.x; acc[0][1] += i0 * w.y; acc[0][2] += i0 * w.z; acc[0][3] += i0 * w.w;
      acc[1][0] += i1 * w.x; acc[1][1] += i1 * w.y; acc[1][2] += i1 * w.z; acc[1][3] += i1 * w.w;
    }
  }
  #pragma unroll
  for (int mi = 0; mi < 2; ++mi)
    #pragma unroll
    for (int ji = 0; ji < 4; ++ji) {
      int j = j0 + 4 * jq + ji;
      float v = acc[mi][ji] + bias[j];
      if (relu) v = fmaxf(v, 0.0f);
      out[(size_t)(m0 + 2 * mq + mi) * J + j] = v;
    }
}

// ---------------- weight arrangement into MFMA-fragment order, 3-way bf16 split
// layout: ((((kc*NT + ht)*G + g)*3 + s)*64 + lane)*8 + j ; value = split_s(B[k][n])
// k = kc*32 + (lane>>4)*8 + j ; n = g*512 + ht*16 + (lane&15)   (for G=3 gate layouts)
__device__ inline void split3_store(float v, ushort_t* p0, ushort_t* p1, ushort_t* p2) {
  __bf16 t0 = (__bf16)v; float r1 = v - (float)t0;
  __bf16 t1 = (__bf16)r1; float r2 = r1 - (float)t1;
  __bf16 t2 = (__bf16)r2;
  *p0 = __builtin_bit_cast(ushort_t, t0);
  *p1 = __builtin_bit_cast(ushort_t, t1);
  *p2 = __builtin_bit_cast(ushort_t, t2);
}

__global__ __launch_bounds__(256) void arrangeB1_k(const float* __restrict__ w_ih1,
                                                   const float* __restrict__ w_hh1,
                                                   ushort_t* __restrict__ dst) {
  int id = blockIdx.x * 256 + threadIdx.x;          // (kc,ht,g,l): 32*32*3*64
  if (id >= 32 * 32 * 3 * 64) return;
  int l = id & 63; int rest = id >> 6;
  int g = rest % 3; rest /= 3;
  int ht = rest & 31; int kc = rest >> 5;
  int n = g * 512 + ht * 16 + (l & 15);
  int kbase = kc * 32 + (l >> 4) * 8;
  size_t ob = (size_t)((kc * 32 + ht) * 3 + g) * 1536 + (size_t)l * 8;
  #pragma unroll
  for (int j = 0; j < 8; ++j) {
    int k = kbase + j;
    float v = (k < 512) ? w_ih1[(size_t)n * 512 + k] : w_hh1[(size_t)n * 512 + (k - 512)];
    split3_store(v, dst + ob + j, dst + ob + 512 + j, dst + ob + 1024 + j);
  }
}

__global__ __launch_bounds__(256) void arrangeA0_k(const float* __restrict__ w_hh0,
                                                   const float* __restrict__ w_ih0,
                                                   ushort_t* __restrict__ dst) {
  int id = blockIdx.x * 256 + threadIdx.x;          // (kc,ht,g,l): 18*32*3*64
  if (id >= 18 * 32 * 3 * 64) return;
  int l = id & 63; int rest = id >> 6;
  int g = rest % 3; rest /= 3;
  int ht = rest & 31; int kc = rest >> 5;
  int n = g * 512 + ht * 16 + (l & 15);
  int kbase = kc * 32 + (l >> 4) * 8;
  size_t ob = (size_t)((kc * 32 + ht) * 3 + g) * 1536 + (size_t)l * 8;
  #pragma unroll
  for (int j = 0; j < 8; ++j) {
    int k = kbase + j;
    float v = (k < 512) ? w_hh0[(size_t)n * 512 + k] : w_ih0[(size_t)n * 576 + (k - 512)];
    split3_store(v, dst + ob + j, dst + ob + 512 + j, dst + ob + 1024 + j);
  }
}

__global__ __launch_bounds__(256) void arrangeH_k(const float* __restrict__ wtH,
                                                  ushort_t* __restrict__ dst) {
  int id = blockIdx.x * 256 + threadIdx.x;          // (kc,ht,l): 16*4*64
  if (id >= 16 * 4 * 64) return;
  int l = id & 63; int rest = id >> 6;
  int ht = rest & 3; int kc = rest >> 2;
  int c = ht * 16 + (l & 15);
  int kbase = kc * 32 + (l >> 4) * 8;
  size_t ob = (size_t)(kc * 4 + ht) * 1536 + (size_t)l * 8;
  #pragma unroll
  for (int j = 0; j < 8; ++j) {
    float v = wtH[(size_t)(kbase + j) * 64 + c];
    split3_store(v, dst + ob + j, dst + ob + 512 + j, dst + ob + 1024 + j);
  }
}

// ---------------- MFMA helpers: 6-product split accumulation (fp32-accurate)
__device__ inline bf16x8 ldb8(const ushort_t* p) { return *reinterpret_cast<const bf16x8*>(p); }

#define MFMA_(A, W, C) __builtin_amdgcn_mfma_f32_16x16x32_bf16((A), (W), (C), 0, 0, 0)

__device__ inline void mm6p(f32x4& accA, f32x4& accB,
                            bf16x8 a0A, bf16x8 a1A, bf16x8 a2A,
                            bf16x8 a0B, bf16x8 a1B, bf16x8 a2B,
                            const ushort_t* wb) {
  bf16x8 w0 = ldb8(wb), w1 = ldb8(wb + 512), w2 = ldb8(wb + 1024);
  accA = MFMA_(a0A, w0, accA); accA = MFMA_(a0A, w1, accA); accA = MFMA_(a1A, w0, accA);
  accA = MFMA_(a1A, w1, accA); accA = MFMA_(a0A, w2, accA); accA = MFMA_(a2A, w0, accA);
  accB = MFMA_(a0B, w0, accB); accB = MFMA_(a0B, w1, accB); accB = MFMA_(a1B, w0, accB);
  accB = MFMA_(a1B, w1, accB); accB = MFMA_(a0B, w2, accB); accB = MFMA_(a2B, w0, accB);
}

__device__ inline f32x4 mm6(f32x4 acc, bf16x8 a0, bf16x8 a1, bf16x8 a2, const ushort_t* wb) {
  bf16x8 w0 = ldb8(wb), w1 = ldb8(wb + 512), w2 = ldb8(wb + 1024);
  acc = MFMA_(a0, w0, acc); acc = MFMA_(a0, w1, acc); acc = MFMA_(a1, w0, acc);
  acc = MFMA_(a1, w1, acc); acc = MFMA_(a0, w2, acc); acc = MFMA_(a2, w0, acc);
  return acc;
}

struct HeadPtrs {
  const float *time_b, *visit_b, *tcont_b, *irr0_b, *irr1_b, *cat0_b, *cat1_b;
};

__device__ inline float head_bias(const HeadPtrs& hp, int c) {
  if (c == 0) return hp.time_b[0];
  if (c == 1) return hp.visit_b[0];
  if (c < 34) return hp.tcont_b[c - 2];
  if (c == 34) return hp.irr0_b[0];
  if (c == 35) return hp.irr1_b[0];
  if (c < 44) return hp.cat0_b[c - 36];
  return hp.cat1_b[c - 44];
}

// ---------------- fused per-step MFMA kernel (no LDS, no barriers)
// blk [0,128): job B (h1 update, step s-1);  blk [128,256): job A (h0 update, step s);
// blk [256,272): job C (head logits for t=s-2)
__global__ __launch_bounds__(128) void step_k(int s,
    const float* __restrict__ z_temporal,
    const float* __restrict__ b_hh0,
    const float* __restrict__ b_ih1, const float* __restrict__ b_hh1,
    float* __restrict__ ws, HeadPtrs hp)
{
  int blk = blockIdx.x, tid = threadIdx.x;
  int wv = tid >> 6, l = tid & 63, lm = l & 15, lq = l >> 4;
  const ushort_t* h0sAll = (const ushort_t*)(ws + H0S);
  const ushort_t* h1sAll = (const ushort_t*)(ws + H1S);

  if (blk < 128) {
    // ---- job B: h1_{s-1} = GRUcell1(h0_{s-1}, h1_{s-2}); s in [1,256]
    if (s < 1 || s > 256) return;
    int bt = blk >> 4, hg = blk & 15;
    int b0 = bt * 32, hc = hg * 32 + wv * 16, ht = hg * 2 + wv;
    const ushort_t* h0s = h0sAll + (size_t)((s - 1) & 1) * 393216;
    const ushort_t* h1s = h1sAll + (size_t)(s & 1) * 393216;
    const float* h1f_old = ws + H1F + (size_t)(s & 1) * 131072;
    float* h1f_cur = ws + H1F + (size_t)((s - 1) & 1) * 131072;
    ushort_t* h1s_cur = (ushort_t*)(ws + H1S) + (size_t)((s - 1) & 1) * 393216;
    const ushort_t* wB = (const ushort_t*)(ws + WB1) + (size_t)ht * 4608 + (size_t)l * 8;
    size_t aoff0 = (size_t)(b0 + lm) * 512 + (size_t)lq * 8;
    size_t aoff1 = aoff0 + 16 * 512;
    f32x4 vr[2] = {}; f32x4 vz[2] = {}; f32x4 vni[2] = {}; f32x4 vnh[2] = {};
    #pragma unroll 2
    for (int kc = 0; kc < 32; ++kc) {
      const ushort_t* as = (kc < 16) ? h0s : h1s;
      int kk = (kc & 15) * 32;
      bf16x8 a00 = ldb8(as + aoff0 + kk);
      bf16x8 a10 = ldb8(as + 131072 + aoff0 + kk);
      bf16x8 a20 = ldb8(as + 262144 + aoff0 + kk);
      bf16x8 a01 = ldb8(as + aoff1 + kk);
      bf16x8 a11 = ldb8(as + 131072 + aoff1 + kk);
      bf16x8 a21 = ldb8(as + 262144 + aoff1 + kk);
      const ushort_t* wb = wB + (size_t)kc * 147456;
      mm6p(vr[0], vr[1], a00, a10, a20, a01, a11, a21, wb);
      mm6p(vz[0], vz[1], a00, a10, a20, a01, a11, a21, wb + 1536);
      if (kc < 16) mm6p(vni[0], vni[1], a00, a10, a20, a01, a11, a21, wb + 3072);
      else         mm6p(vnh[0], vnh[1], a00, a10, a20, a01, a11, a21, wb + 3072);
    }
    #pragma unroll
    for (int sub = 0; sub < 2; ++sub)
      #pragma unroll
      for (int r = 0; r < 4; ++r) {
        int b = b0 + sub * 16 + lq * 4 + r;
        int h = hc + lm;
        float srr = vr[sub][r] + b_ih1[h] + b_hh1[h];
        float szz = vz[sub][r] + b_ih1[512 + h] + b_hh1[512 + h];
        float sni = vni[sub][r] + b_ih1[1024 + h];
        float snh = vnh[sub][r] + b_hh1[1024 + h];
        float rg = sigmoidf_(srr), zg = sigmoidf_(szz);
        float n = tanhf(sni + rg * snh);
        float hold = h1f_old[(size_t)b * 512 + h];
        float hnew = (1.0f - zg) * n + zg * hold;
        h1f_cur[(size_t)b * 512 + h] = hnew;
        __bf16 t0 = (__bf16)hnew; float r1 = hnew - (float)t0;
        __bf16 t1 = (__bf16)r1;   float r2 = r1 - (float)t1;
        __bf16 t2 = (__bf16)r2;
        size_t ho = (size_t)b * 512 + h;
        h1s_cur[ho]          = __builtin_bit_cast(ushort_t, t0);
        h1s_cur[131072 + ho] = __builtin_bit_cast(ushort_t, t1);
        h1s_cur[262144 + ho] = __builtin_bit_cast(ushort_t, t2);
      }
  } else if (blk < 256) {
    // ---- job A: h0_s = GRUcell0(z_s ++ static, h0_{s-1}); s in [0,255]
    if (s > 255) return;
    int ba = blk - 128;
    int bt = ba >> 4, hg = ba & 15;
    int b0 = bt * 32, hc = hg * 32 + wv * 16, ht = hg * 2 + wv;
    const ushort_t* h0s_prev = h0sAll + (size_t)((s + 1) & 1) * 393216;
    const float* h0f_old = ws + H0F + (size_t)((s + 1) & 1) * 131072;
    float* h0f_cur = ws + H0F + (size_t)(s & 1) * 131072;
    ushort_t* h0s_cur = (ushort_t*)(ws + H0S) + (size_t)(s & 1) * 393216;
    const float* acc0 = ws + ACC0;
    const ushort_t* wA = (const ushort_t*)(ws + WA0) + (size_t)ht * 4608 + (size_t)l * 8;
    size_t aoff0 = (size_t)(b0 + lm) * 512 + (size_t)lq * 8;
    size_t aoff1 = aoff0 + 16 * 512;
    f32x4 vr[2] = {}; f32x4 vz[2] = {}; f32x4 vni[2] = {}; f32x4 vnh[2] = {};
    #pragma unroll 2
    for (int kc = 0; kc < 18; ++kc) {
      bf16x8 a00, a10, a20, a01, a11, a21;
      if (kc < 16) {
        int kk = kc * 32;
        a00 = ldb8(h0s_prev + aoff0 + kk);
        a10 = ldb8(h0s_prev + 131072 + aoff0 + kk);
        a20 = ldb8(h0s_prev + 262144 + aoff0 + kk);
        a01 = ldb8(h0s_prev + aoff1 + kk);
        a11 = ldb8(h0s_prev + 131072 + aoff1 + kk);
        a21 = ldb8(h0s_prev + 262144 + aoff1 + kk);
      } else {
        int kz = (kc - 16) * 32 + lq * 8;
        #pragma unroll
        for (int sub = 0; sub < 2; ++sub) {
          const float* zp = z_temporal + ((size_t)(b0 + sub * 16 + lm) * 256 + s) * 64 + kz;
          float4 q0 = *(const float4*)(zp);
          float4 q1 = *(const float4*)(zp + 4);
          float vals[8] = {q0.x, q0.y, q0.z, q0.w, q1.x, q1.y, q1.z, q1.w};
          bf16x8 b0v, b1v, b2v;
          #pragma unroll
          for (int j = 0; j < 8; ++j) {
            float v = vals[j];
            __bf16 t0 = (__bf16)v; float r1 = v - (float)t0;
            __bf16 t1 = (__bf16)r1; float r2 = r1 - (float)t1;
            b0v[j] = t0; b1v[j] = t1; b2v[j] = (__bf16)r2;
          }
          if (sub == 0) { a00 = b0v; a10 = b1v; a20 = b2v; }
          else          { a01 = b0v; a11 = b1v; a21 = b2v; }
        }
      }
      const ushort_t* wb = wA + (size_t)kc * 147456;
      mm6p(vr[0], vr[1], a00, a10, a20, a01, a11, a21, wb);
      mm6p(vz[0], vz[1], a00, a10, a20, a01, a11, a21, wb + 1536);
      if (kc < 16) mm6p(vnh[0], vnh[1], a00, a10, a20, a01, a11, a21, wb + 3072);
      else         mm6p(vni[0], vni[1], a00, a10, a20, a01, a11, a21, wb + 3072);
    }
    #pragma unroll
    for (int sub = 0; sub < 2; ++sub)
      #pragma unroll
      for (int r = 0; r < 4; ++r) {
        int b = b0 + sub * 16 + lq * 4 + r;
        int h = hc + lm;
        const float* ac = acc0 + (size_t)b * 1536;
        float srr = vr[sub][r] + ac[h] + b_hh0[h];
        float szz = vz[sub][r] + ac[512 + h] + b_hh0[512 + h];
        float sni = vni[sub][r] + ac[1024 + h];
        float snh = vnh[sub][r] + b_hh0[1024 + h];
        float rg = sigmoidf_(srr), zg = sigmoidf_(szz);
        float n = tanhf(sni + rg * snh);
        float hold = h0f_old[(size_t)b * 512 + h];
        float hnew = (1.0f - zg) * n + zg * hold;
        h0f_cur[(size_t)b * 512 + h] = hnew;
        __bf16 t0 = (__bf16)hnew; float r1 = hnew - (float)t0;
        __bf16 t1 = (__bf16)r1;   float r2 = r1 - (float)t1;
        __bf16 t2 = (__bf16)r2;
        size_t ho = (size_t)b * 512 + h;
        h0s_cur[ho]          = __builtin_bit_cast(ushort_t, t0);
        h0s_cur[131072 + ho] = __builtin_bit_cast(ushort_t, t1);
        h0s_cur[262144 + ho] = __builtin_bit_cast(ushort_t, t2);
      }
  } else {
    // ---- job C: head logits for t = s-2 from h1_{s-2}; s in [2,257]
    if (s < 2) return;
    int bt = blk - 256;
    int b0 = bt * 16, c0 = wv * 32;
    int t = s - 2;
    const ushort_t* h1s = h1sAll + (size_t)(s & 1) * 393216;
    const ushort_t* wH = (const ushort_t*)(ws + WH) + (size_t)l * 8;
    size_t aoff = (size_t)(b0 + lm) * 512 + (size_t)lq * 8;
    f32x4 va0 = {}; f32x4 va1 = {};
    #pragma unroll 2
    for (int kc = 0; kc < 16; ++kc) {
      int kk = kc * 32;
      bf16x8 a0 = ldb8(h1s + aoff + kk);
      bf16x8 a1 = ldb8(h1s + 131072 + aoff + kk);
      bf16x8 a2 = ldb8(h1s + 262144 + aoff + kk);
      const ushort_t* wb = wH + (size_t)(kc * 4 + (c0 >> 4)) * 1536;
      va0 = mm6(va0, a0, a1, a2, wb);
      va1 = mm6(va1, a0, a1, a2, wb + 1536);
    }
    float* lg = ws + LOGB;
    #pragma unroll
    for (int ct = 0; ct < 2; ++ct)
      #pragma unroll
      for (int r = 0; r < 4; ++r) {
        int b = b0 + lq * 4 + r;
        int c = c0 + ct * 16 + lm;
        if (c < 60) {
          float v = (ct ? va1[r] : va0[r]) + head_bias(hp, c);
          lg[((size_t)b * 256 + t) * 64 + c] = v;
        }
      }
  }
}

// ---------------- static heads
__global__ __launch_bounds__(64) void static_heads_k(const float* __restrict__ sh_buf,
    const float* __restrict__ scont_w, const float* __restrict__ scont_b,
    const float* __restrict__ scat_w, const float* __restrict__ scat_b,
    float* __restrict__ out, unsigned ks0, unsigned ks1)
{
  __shared__ float hrow[512];
  __shared__ float xl[10];
  __shared__ float yv[10];
  __shared__ int argsh;
  int b = blockIdx.x, tid = threadIdx.x;
  const float* hr = sh_buf + (size_t)b * 512;
  for (int i = tid; i < 512; i += 64) hrow[i] = hr[i];
  __syncthreads();
  if (tid < 16) {
    float a = 0.f;
    const float* w = scont_w + (size_t)tid * 512;
    for (int k = 0; k < 512; ++k) a += hrow[k] * w[k];
    out[O_SCONT + (size_t)b * 16 + tid] = a + scont_b[tid];
  }
  if (tid < 10) {
    float a = 0.f;
    const float* w = scat_w + (size_t)tid * 512;
    for (int k = 0; k < 512; ++k) a += hrow[k] * w[k];
    a += scat_b[tid];
    float u = rng_uniform_n(ks0, ks1, (unsigned)(b * 10 + tid), 2560u);
    u = fmaxf(1e-9f, u + 1e-9f);
    float g = -logf(-logf(u));
    xl[tid] = a + g;
  }
  __syncthreads();
  if (tid == 0) {
    float m = xl[0];
    for (int c = 1; c < 10; ++c) m = fmaxf(m, xl[c]);
    float ssum = 0.f;
    for (int c = 0; c < 10; ++c) { yv[c] = expf(xl[c] - m); ssum += yv[c]; }
    int arg = 0; float best = -1.0f;
    for (int c = 0; c < 10; ++c) { yv[c] = yv[c] / ssum; if (yv[c] > best) { best = yv[c]; arg = c; } }
    argsh = arg;
  }
  __syncthreads();
  if (tid < 10) {
    float y = yv[tid];
    out[O_SCAT + (size_t)b * 10 + tid] = (tid == argsh) ? ((1.0f + y) - y) : 0.0f;
  }
}

// ---------------- final scans + sampling + emission
struct Keys { unsigned kv0, kv1, ki00, ki01, ki10, ki11, kc00, kc01, kc10, kc11; };

__global__ __launch_bounds__(256) void final_k(const float* __restrict__ ws, float* __restrict__ out, Keys ky)
{
  __shared__ float sh[256];
  __shared__ unsigned shu[256];
  int b = blockIdx.x, t = threadIdx.x;
  int idx = b * 256 + t;
  const float* lg = ws + LOGB + (size_t)idx * 64;
  float l0 = lg[0], l1 = lg[1], l34 = lg[34], l35 = lg[35];

  float dt = fmaxf(l0, 0.0f) + log1pf(expf(-fabsf(l0)));
  sh[t] = dt; __syncthreads();
  for (int off = 1; off < 256; off <<= 1) {
    float v = (t >= off) ? sh[t - off] : 0.0f;
    __syncthreads();
    sh[t] += v;
    __syncthreads();
  }
  float vt = sh[t];
  float denom = sh[255] + 1e-8f;
  out[O_VTIME + idx] = vt / denom;
  __syncthreads();

  float pv = sigmoidf_(l1);
  float uv = rng_uniform_n(ky.kv0, ky.kv1, (unsigned)idx, 65536u);
  shu[t] = (t == 0) ? 1u : (uv < pv ? 1u : 0u);
  __syncthreads();
  for (int off = 1; off < 256; off <<= 1) {
    unsigned v = (t >= off) ? shu[t - off] : 1u;
    __syncthreads();
    shu[t] &= v;
    __syncthreads();
  }
  float mask = (float)shu[t];
  out[O_VMASK + idx] = mask;
  __syncthreads();

  {
    float hz = sigmoidf_(l34);
    float u = rng_uniform_n(ky.ki00, ky.ki01, (unsigned)idx, 65536u);
    shu[t] = (u < hz) ? 1u : 0u;
    __syncthreads();
    for (int off = 1; off < 256; off <<= 1) {
      unsigned v = (t >= off) ? shu[t - off] : 0u;
      __syncthreads();
      shu[t] |= v;
      __syncthreads();
    }
    float st = (float)shu[t];
    out[O_IRR0 + (size_t)idx * 2]     = (1.0f - st) * mask;
    out[O_IRR0 + (size_t)idx * 2 + 1] = st * mask;
    __syncthreads();
  }
  {
    float hz = sigmoidf_(l35);
    float u = rng_uniform_n(ky.ki10, ky.ki11, (unsigned)idx, 65536u);
    shu[t] = (u < hz) ? 1u : 0u;
    __syncthreads();
    for (int off = 1; off < 256; off <<= 1) {
      unsigned v = (t >= off) ? shu[t - off] : 0u;
      __syncthreads();
      shu[t] |= v;
      __syncthreads();
    }
    float st = (float)shu[t];
    out[O_IRR1 + (size_t)idx * 2]     = (1.0f - st) * mask;
    out[O_IRR1 + (size_t)idx * 2 + 1] = st * mask;
  }

  #pragma unroll
  for (int c = 0; c < 32; ++c)
    out[O_TCONT + (size_t)idx * 32 + c] = lg[2 + c] * mask;

  {
    float x[8], y[8];
    float m = -1e30f;
    #pragma unroll
    for (int c = 0; c < 8; ++c) {
      float u = rng_uniform_n(ky.kc00, ky.kc01, (unsigned)idx * 8u + c, 524288u);
      u = fmaxf(1e-9f, u + 1e-9f);
      float g = -logf(-logf(u));
      x[c] = lg[36 + c] + g;
      m = fmaxf(m, x[c]);
    }
    float ssum = 0.f;
    #pragma unroll
    for (int c = 0; c < 8; ++c) { y[c] = expf(x[c] - m); ssum += y[c]; }
    int arg = 0; float best = -1.0f;
    #pragma unroll
    for (int c = 0; c < 8; ++c) { y[c] /= ssum; if (y[c] > best) { best = y[c]; arg = c; } }
    #pragma unroll
    for (int c = 0; c < 8; ++c)
      out[O_CAT0 + (size_t)idx * 8 + c] = (c == arg) ? ((1.0f + y[c]) - y[c]) * mask : 0.0f;
  }
  {
    float x[16], y[16];
    float m = -1e30f;
    #pragma unroll
    for (int c = 0; c < 16; ++c) {
      float u = rng_uniform_n(ky.kc10, ky.kc11, (unsigned)idx * 16u + c, 1048576u);
      u = fmaxf(1e-9f, u + 1e-9f);
      float g = -logf(-logf(u));
      x[c] = lg[44 + c] + g;
      m = fmaxf(m, x[c]);
    }
    float ssum = 0.f;
    #pragma unroll
    for (int c = 0; c < 16; ++c) { y[c] = expf(x[c] - m); ssum += y[c]; }
    int arg = 0; float best = -1.0f;
    #pragma unroll
    for (int c = 0; c < 16; ++c) { y[c] /= ssum; if (y[c] > best) { best = y[c]; arg = c; } }
    #pragma unroll
    for (int c = 0; c < 16; ++c)
      out[O_CAT1 + (size_t)idx * 16 + c] = (c == arg) ? ((1.0f + y[c]) - y[c]) * mask : 0.0f;
  }
}

// ---------------- host entry
extern "C" void kernel_launch(void* const* d_in, const int* in_sizes, int n_in,
                              void* d_out, int out_size, void* d_ws, size_t ws_size,
                              hipStream_t stream)
{
  (void)in_sizes; (void)n_in; (void)out_size; (void)ws_size;
  const float* z_static   = (const float*)d_in[0];
  const float* z_temporal = (const float*)d_in[1];
  const float* fc1_w = (const float*)d_in[2];
  const float* fc1_b = (const float*)d_in[3];
  const float* fc2_w = (const float*)d_in[4];
  const float* fc2_b = (const float*)d_in[5];
  const float* w_ih0 = (const float*)d_in[6];
  const float* w_hh0 = (const float*)d_in[7];
  const float* b_ih0 = (const float*)d_in[8];
  const float* b_hh0 = (const float*)d_in[9];
  const float* w_ih1 = (const float*)d_in[10];
  const float* w_hh1 = (const float*)d_in[11];
  const float* b_ih1 = (const float*)d_in[12];
  const float* b_hh1 = (const float*)d_in[13];
  const float* time_w = (const float*)d_in[14];
  const float* time_b = (const float*)d_in[15];
  const float* visit_w = (const float*)d_in[16];
  const float* visit_b = (const float*)d_in[17];
  const float* tcont_w = (const float*)d_in[18];
  const float* tcont_b = (const float*)d_in[19];
  const float* irr0_w = (const float*)d_in[20];
  const float* irr0_b = (const float*)d_in[21];
  const float* irr1_w = (const float*)d_in[22];
  const float* irr1_b = (const float*)d_in[23];
  const float* cat0_w = (const float*)d_in[24];
  const float* cat0_b = (const float*)d_in[25];
  const float* cat1_w = (const float*)d_in[26];
  const float* cat1_b = (const float*)d_in[27];
  const float* scont_w = (const float*)d_in[28];
  const float* scont_b = (const float*)d_in[29];
  const float* scat_w = (const float*)d_in[30];
  const float* scat_b = (const float*)d_in[31];
  float* ws = (float*)d_ws;
  float* out = (float*)d_out;

  // static-path transposes (aliased into LOGB region, consumed pre-loop)
  transpose_k<<<dim3(4, 16), 256, 0, stream>>>(fc1_w, ws + FC1T, 512, 128, 128, 512);
  transpose_k<<<dim3(16, 16), 256, 0, stream>>>(fc2_w, ws + FC2T, 512, 512, 512, 512);
  transpose_k<<<dim3(16, 48), 256, 0, stream>>>(w_ih0 + 64, ws + WIS, 1536, 512, 576, 1536);
  hgather_k<<<64, 128, 0, stream>>>(time_w, visit_w, tcont_w, irr0_w, irr1_w, cat0_w, cat1_w, ws + WTH);

  // static path: static_h, acc0
  gemm_k<<<8 * 16, 128, 0, stream>>>(z_static, ws + FC1T, fc1_b, ws + HID, 256, 128, 512, 1);
  gemm_k<<<8 * 16, 128, 0, stream>>>(ws + HID, ws + FC2T, fc2_b, ws + SHH, 256, 512, 512, 0);
  gemm_k<<<8 * 48, 128, 0, stream>>>(ws + SHH, ws + WIS, b_ih0, ws + ACC0, 256, 512, 1536, 0);

  // arrange MFMA weight fragments (3-way bf16 split)
  arrangeB1_k<<<(32 * 32 * 3 * 64 + 255) / 256, 256, 0, stream>>>(w_ih1, w_hh1, (ushort_t*)(ws + WB1));
  arrangeA0_k<<<(18 * 32 * 3 * 64 + 255) / 256, 256, 0, stream>>>(w_hh0, w_ih0, (ushort_t*)(ws + WA0));
  arrangeH_k<<<(16 * 4 * 64 + 255) / 256, 256, 0, stream>>>(ws + WTH, (ushort_t*)(ws + WH));

  // RNG keys: key(42) = (0,42); 6 children
  unsigned kk[6][2];
#if RNG_PART
  for (int i = 0; i < 6; ++i) tf2x32(0u, 42u, 0u, (unsigned)i, &kk[i][0], &kk[i][1]);
#else
  {
    unsigned flat[12];
    for (int i = 0; i < 6; ++i) {
      unsigned a, bq;
      tf2x32(0u, 42u, (unsigned)i, (unsigned)(6 + i), &a, &bq);
      flat[i] = a; flat[6 + i] = bq;
    }
    for (int i = 0; i < 6; ++i) { kk[i][0] = flat[2 * i]; kk[i][1] = flat[2 * i + 1]; }
  }
#endif
  static_heads_k<<<256, 64, 0, stream>>>(ws + SHH, scont_w, scont_b, scat_w, scat_b, out, kk[5][0], kk[5][1]);

  // zero initial hidden states: f32 ping-pong parity 1 and bf16 splits parity 1
  hipMemsetAsync((void*)(ws + H0F + 131072), 0, 131072 * sizeof(float), stream);
  hipMemsetAsync((void*)(ws + H1F + 131072), 0, 131072 * sizeof(float), stream);
  hipMemsetAsync((void*)((ushort_t*)(ws + H0S) + 393216), 0, 393216 * sizeof(ushort_t), stream);
  hipMemsetAsync((void*)((ushort_t*)(ws + H1S) + 393216), 0, 393216 * sizeof(ushort_t), stream);

  HeadPtrs hp{time_b, visit_b, tcont_b, irr0_b, irr1_b, cat0_b, cat1_b};
  for (int s = 0; s <= 257; ++s)
    step_k<<<272, 128, 0, stream>>>(s, z_temporal, b_hh0, b_ih1, b_hh1, ws, hp);

  Keys ky{kk[0][0], kk[0][1], kk[1][0], kk[1][1], kk[2][0], kk[2][1],
          kk[3][0], kk[3][1], kk[4][0], kk[4][1]};
  final_k<<<256, 256, 0, stream>>>(ws, out, ky);
}